// Round 13
// baseline (455.452 us; speedup 1.0000x reference)
//
#include <hip/hip_runtime.h>
#include <hip/hip_bf16.h>
#include <math.h>

#define B_SZ   32
#define NXX    16384
#define IN_DIM 3
#define DIM    64
#define JM     16
#define MODE   128
#define RANKK  4
#define FC_DIM 128
#define N_LAY  3

typedef __attribute__((ext_vector_type(8))) short bf16x8;
typedef __attribute__((ext_vector_type(4))) float f32x4;
typedef unsigned short u16;

// Fast gelu: v * sigmoid(2u), u = sqrt(2/pi)*(v + 0.044715 v^3).
__device__ __forceinline__ float gelu_fast(float v) {
    float p = v * (0.7978845608f + 0.0356774081f * v * v);
    float e = __expf(-2.f * p);
    return v * __builtin_amdgcn_rcpf(1.f + e);
}
__device__ __forceinline__ u16 to_bf16(float v) {
    __hip_bfloat16 b = __float2bfloat16(v);
    return *(u16*)&b;
}

// ---------------------------------------------------------------------------
__global__ __launch_bounds__(256) void k_zero(float* __restrict__ p, int n) {
    int i = blockIdx.x * 256 + threadIdx.x;
    if (i < n) p[i] = 0.f;
}

// float4 variant for the per-layer 2MB clear (ybuf+xh).  grid 512 x 256.
__global__ __launch_bounds__(256) void k_zero4(float* __restrict__ p) {
    int i = blockIdx.x * 256 + threadIdx.x;
    *(float4*)(p + (size_t)i * 4) = make_float4(0.f, 0.f, 0.f, 0.f);
}

// H[j,k,l] bf16 row-major (l contig = A-frag-ready for m=k, kk=l).
__global__ __launch_bounds__(256) void k_build_H(
        const float* __restrict__ Dout, const float* __restrict__ Din,
        const float* __restrict__ product, const float* __restrict__ A,
        const float* __restrict__ Bm, u16* __restrict__ Hbf) {
    int idx = blockIdx.x * 256 + threadIdx.x;
    int j = idx >> 14;
    int k = (idx >> 7) & 127;
    int l = idx & 127;
    float v = Dout[j * MODE + k] * Din[j * MODE + l] * product[k * MODE + l];
#pragma unroll
    for (int r = 0; r < RANKK; ++r)
        v += A[(j * RANKK + r) * MODE + k] * Bm[(j * RANKK + r) * MODE + l];
    Hbf[idx] = to_bf16(v);
}

// WsT[lay][j][o][i] = Wsp[lay][i][o][j] bf16 (i contig).  grid 768 x 256.
__global__ __launch_bounds__(256) void k_setup_wst(
        const float* __restrict__ Wsp, u16* __restrict__ WsT) {
    int idx = blockIdx.x * 256 + threadIdx.x;   // ((lay*16+j)*64+o)*64+i
    int i = idx & 63, o = (idx >> 6) & 63, j = (idx >> 12) & 15, lay = idx >> 16;
    WsT[idx] = to_bf16(Wsp[(((size_t)lay * 64 + i) * 64 + o) * 16 + j]);
}

// bases (fp32 [x][k]) -> FRAG-MAJOR single bf16 plane.  grid 8192 x 256.
__global__ __launch_bounds__(256) void k_setup_bases(
        const float* __restrict__ bases, u16* __restrict__ bh) {
    int idx = blockIdx.x * 256 + threadIdx.x;
    int x = idx >> 7, k = idx & 127;
    size_t off = (size_t)(k >> 3) * 131072 + (size_t)x * 8 + (k & 7);
    bh[off] = to_bf16(bases[idx]);
}

// wbT[l][x] = wbases[x][l], single bf16 plane.  grid (512, 4) x 256, LDS-tiled.
__global__ __launch_bounds__(256) void k_setup_wbT(
        const float* __restrict__ wb, u16* __restrict__ Th) {
    __shared__ float tile[32][33];
    int bx = blockIdx.x, bl = blockIdx.y;
    int t = threadIdx.x;
    int i = t >> 5, jj = t & 31;
#pragma unroll
    for (int r = 0; r < 4; ++r)
        tile[i + r * 8][jj] = wb[(size_t)(bx * 32 + i + r * 8) * MODE + bl * 32 + jj];
    __syncthreads();
#pragma unroll
    for (int r = 0; r < 4; ++r) {
        int l = bl * 32 + i + r * 8;
        int x = bx * 32 + jj;
        Th[(size_t)l * NXX + x] = to_bf16(tile[jj][i + r * 8]);
    }
}

// W1T[f*64+c] = W1[c*128+f] single bf16 plane.  grid 32 x 256
__global__ __launch_bounds__(256) void k_setup_w1t(
        const float* __restrict__ W1, u16* __restrict__ wh) {
    int i = blockIdx.x * 256 + threadIdx.x;
    int f = i >> 6, c = i & 63;
    wh[i] = to_bf16(W1[c * FC_DIM + f]);
}

// fc0: h[b,x,c] (single bf16 plane), coalesced ushort8 stores.
// grid (512, 32) x 256.
__global__ __launch_bounds__(256) void k_fc0(
        const float* __restrict__ x, const float* __restrict__ W0,
        const float* __restrict__ b0, u16* __restrict__ hh) {
    __shared__ float w0s[IN_DIM * DIM + DIM];
    int t = threadIdx.x;
    if (t < IN_DIM * DIM) w0s[t] = W0[t];
    if (t < DIM) w0s[IN_DIM * DIM + t] = b0[t];
    __syncthreads();
    int b = blockIdx.y;
    int xi = blockIdx.x * 32 + (t >> 3);
    int c8 = (t & 7) * 8;
    const float* xp = x + ((size_t)b * NXX + xi) * IN_DIM;
    float x0 = xp[0], x1 = xp[1], x2 = xp[2];
    u16 rh[8];
#pragma unroll
    for (int i = 0; i < 8; ++i) {
        int c = c8 + i;
        float v = x0 * w0s[c] + x1 * w0s[DIM + c] + x2 * w0s[2 * DIM + c]
                + w0s[3 * DIM + c];
        rh[i] = to_bf16(v);
    }
    size_t o = ((size_t)(b << 14) + xi) * 64 + c8;
    *(ushort4*)(hh + o)     = make_ushort4(rh[0], rh[1], rh[2], rh[3]);
    *(ushort4*)(hh + o + 4) = make_ushort4(rh[4], rh[5], rh[6], rh[7]);
}

// ---------------------------------------------------------------------------
// Spectral via MFMA: xh[b][c][l] += sum_x h[b][x][c] * wbases[x][l]
// Double-buffered Ash (1 barrier/step), reg prefetch, XCD swizzle.
// r13: PART mode uses grid (32,32) with 512-x slabs (4 blocks/CU, 16
// waves/CU — no atomics so the r9 atomic-count trade inverts); atomic
// fallback keeps grid (32,16) with 1024-x slabs (r9-measured best).
#define SPAD 72
template <bool PART>
__global__ __launch_bounds__(256) void k_spectral_mfma(
        const u16* __restrict__ Hh,
        const u16* __restrict__ Wh,
        float* __restrict__ xh,
        float* __restrict__ xh_part) {
    constexpr int XSPAN = PART ? 512 : 1024;
    constexpr int CHUNK = PART ? 128 : 64;     // blocks per XCD in swizzle
    __shared__ u16 Ash[2][64 * SPAD];
    int t = threadIdx.x;
    int wave = t >> 6, lane = t & 63, quad = lane >> 4, l16 = lane & 15;
    int lin = blockIdx.y * 32 + blockIdx.x;
    int swz = (lin & 7) * CHUNK + (lin >> 3);  // XCD-contiguous
    int b = swz & 31;
    int slab = swz >> 5;
    int x0 = slab * XSPAN;
    int cq = (t & 15) * 4;
    int xq = (t >> 4) * 4;
    int colw = (xq + ((t & 7) << 3)) & 63;
    const u16* srch = Hh + ((size_t)(b << 14) + x0 + xq) * 64 + cq;
    int l0 = wave * 32;
    const u16* w0h = Wh + (size_t)(l0 + l16) * NXX + x0;
    const u16* w1h = Wh + (size_t)(l0 + 16 + l16) * NXX + x0;
    ushort4 r0, r1, r2, r3;
    {
        const u16* s = srch;
        r0 = *(const ushort4*)(s);
        r1 = *(const ushort4*)(s + 64);
        r2 = *(const ushort4*)(s + 128);
        r3 = *(const ushort4*)(s + 192);
    }
    f32x4 acc[4][2] = {};
    int cur = 0;
    for (int kt = 0; kt < XSPAN; kt += 64) {
        u16* A = &Ash[cur][0];
        *(ushort4*)&A[(cq + 0) * SPAD + colw] = make_ushort4(r0.x, r1.x, r2.x, r3.x);
        *(ushort4*)&A[(cq + 1) * SPAD + colw] = make_ushort4(r0.y, r1.y, r2.y, r3.y);
        *(ushort4*)&A[(cq + 2) * SPAD + colw] = make_ushort4(r0.z, r1.z, r2.z, r3.z);
        *(ushort4*)&A[(cq + 3) * SPAD + colw] = make_ushort4(r0.w, r1.w, r2.w, r3.w);
        if (kt + 64 < XSPAN) {   // prefetch next slab; completes during MFMA
            const u16* s = srch + (size_t)(kt + 64) * 64;
            r0 = *(const ushort4*)(s);
            r1 = *(const ushort4*)(s + 64);
            r2 = *(const ushort4*)(s + 128);
            r3 = *(const ushort4*)(s + 192);
        }
        __builtin_amdgcn_sched_barrier(0);
        __syncthreads();        // single barrier per step (dbuf)
#pragma unroll
        for (int k0 = 0; k0 < 64; k0 += 32) {
            bf16x8 afh[4];
#pragma unroll
            for (int ct = 0; ct < 4; ++ct) {
                int rr = ct * 16 + l16;
                int ro = rr * SPAD + (((k0 + quad * 8) + (((rr >> 2) & 7) << 3)) & 63);
                afh[ct] = *(const bf16x8*)&A[ro];
            }
            int go = kt + k0 + quad * 8;
            bf16x8 b0h = *(const bf16x8*)(w0h + go);
            bf16x8 b1h = *(const bf16x8*)(w1h + go);
#pragma unroll
            for (int ct = 0; ct < 4; ++ct) {
                acc[ct][0] = __builtin_amdgcn_mfma_f32_16x16x32_bf16(afh[ct], b0h, acc[ct][0], 0, 0, 0);
                acc[ct][1] = __builtin_amdgcn_mfma_f32_16x16x32_bf16(afh[ct], b1h, acc[ct][1], 0, 0, 0);
            }
        }
        cur ^= 1;
    }
    if (PART) {
        float* xp = xh_part + ((size_t)slab * 32 + b) * 8192;
#pragma unroll
        for (int ct = 0; ct < 4; ++ct)
#pragma unroll
            for (int lt = 0; lt < 2; ++lt)
#pragma unroll
                for (int r = 0; r < 4; ++r)
                    xp[(ct * 16 + quad * 4 + r) * 128 + l0 + lt * 16 + l16] =
                        acc[ct][lt][r];
    } else {
        float* xb = xh + (size_t)(b << 6) * 128;
#pragma unroll
        for (int ct = 0; ct < 4; ++ct)
#pragma unroll
            for (int lt = 0; lt < 2; ++lt)
#pragma unroll
                for (int r = 0; r < 4; ++r)
                    atomicAdd(xb + (size_t)(ct * 16 + quad * 4 + r) * 128 + l0 + lt * 16 + l16,
                              acc[ct][lt][r]);
    }
}

// reduce 32 xh partials -> xh.  grid 256 x 256 (float4 per thread).
__global__ __launch_bounds__(256) void k_reduce_xh(
        const float* __restrict__ part, float* __restrict__ xh) {
    size_t i4 = ((size_t)blockIdx.x * 256 + threadIdx.x) * 4;
    float4 s = make_float4(0.f, 0.f, 0.f, 0.f);
#pragma unroll
    for (int sl = 0; sl < 32; ++sl) {
        float4 v = *(const float4*)(part + (size_t)sl * 262144 + i4);
        s.x += v.x; s.y += v.y; s.z += v.z; s.w += v.w;
    }
    *(float4*)(xh + i4) = s;
}

// ---------------------------------------------------------------------------
// hmix via MFMA.  One block per (b, j):
//   phase 1: T[k][i] = sum_l H[j][k][l] * xh[b][i][l]
//   phase 2: y[o][k] contribution for this j.
// No inter-phase barrier (Ts rows wave-private).
#define XPAD 136
#define TPAD 72
template <bool PART>
__global__ __launch_bounds__(256) void k_hmix_mfma(
        const float* __restrict__ xh, const u16* __restrict__ Hbf,
        const u16* __restrict__ WsT, float* __restrict__ y,
        float* __restrict__ y_part, int lay) {
    __shared__ u16 xsb[64 * XPAD];   // [i][l]
    __shared__ u16 Ts[128 * TPAD];   // [k][i], rows wave-private
    int t = threadIdx.x;
    int wave = t >> 6, lane = t & 63, quad = lane >> 4, l16 = lane & 15;
    int b = blockIdx.x, j = blockIdx.y;
    const float* xb = xh + (size_t)b * DIM * MODE;
#pragma unroll
    for (int it = 0; it < 8; ++it) {
        int idx = it * 1024 + t * 4;
        float4 v = *(const float4*)(xb + idx);
        ushort4 uh;
        uh.x = to_bf16(v.x); uh.y = to_bf16(v.y);
        uh.z = to_bf16(v.z); uh.w = to_bf16(v.w);
        *(ushort4*)&xsb[(idx >> 7) * XPAD + (idx & 127)] = uh;
    }
    __syncthreads();
    int k_base = wave * 32;
    // phase 1
    {
        f32x4 acc[2][4] = {};
        const u16* Hj = Hbf + (size_t)j * MODE * MODE;
#pragma unroll
        for (int l0 = 0; l0 < 128; l0 += 32) {
            bf16x8 af[2], bf[4];
#pragma unroll
            for (int mt = 0; mt < 2; ++mt)
                af[mt] = *(const bf16x8*)(Hj + (size_t)(k_base + mt * 16 + l16) * 128 + l0 + quad * 8);
#pragma unroll
            for (int nt = 0; nt < 4; ++nt)
                bf[nt] = *(const bf16x8*)&xsb[(nt * 16 + l16) * XPAD + l0 + quad * 8];
#pragma unroll
            for (int mt = 0; mt < 2; ++mt)
#pragma unroll
                for (int nt = 0; nt < 4; ++nt)
                    acc[mt][nt] = __builtin_amdgcn_mfma_f32_16x16x32_bf16(af[mt], bf[nt], acc[mt][nt], 0, 0, 0);
        }
#pragma unroll
        for (int mt = 0; mt < 2; ++mt)
#pragma unroll
            for (int nt = 0; nt < 4; ++nt)
#pragma unroll
                for (int r = 0; r < 4; ++r)
                    Ts[(k_base + mt * 16 + quad * 4 + r) * TPAD + nt * 16 + l16] =
                        to_bf16(acc[mt][nt][r]);
    }
    // no barrier: phase 2 reads only this wave's own Ts rows
    {
        f32x4 acc[4][2] = {};
        const u16* Wj = WsT + ((size_t)lay * JM + j) * DIM * DIM;
#pragma unroll
        for (int i0 = 0; i0 < 64; i0 += 32) {
            bf16x8 af[4], bf[2];
#pragma unroll
            for (int mt = 0; mt < 4; ++mt)
                af[mt] = *(const bf16x8*)(Wj + (size_t)(mt * 16 + l16) * 64 + i0 + quad * 8);
#pragma unroll
            for (int nt = 0; nt < 2; ++nt)
                bf[nt] = *(const bf16x8*)&Ts[(k_base + nt * 16 + l16) * TPAD + i0 + quad * 8];
#pragma unroll
            for (int mt = 0; mt < 4; ++mt)
#pragma unroll
                for (int nt = 0; nt < 2; ++nt)
                    acc[mt][nt] = __builtin_amdgcn_mfma_f32_16x16x32_bf16(af[mt], bf[nt], acc[mt][nt], 0, 0, 0);
        }
        if (PART) {
            float* yp = y_part + ((size_t)j * 32 + b) * 8192;
#pragma unroll
            for (int mt = 0; mt < 4; ++mt)
#pragma unroll
                for (int nt = 0; nt < 2; ++nt)
#pragma unroll
                    for (int r = 0; r < 4; ++r)
                        yp[(mt * 16 + quad * 4 + r) * 128 + k_base + nt * 16 + l16] =
                            acc[mt][nt][r];
        } else {
            float* yb = y + (size_t)b * DIM * MODE;
#pragma unroll
            for (int mt = 0; mt < 4; ++mt)
#pragma unroll
                for (int nt = 0; nt < 2; ++nt)
#pragma unroll
                    for (int r = 0; r < 4; ++r)
                        atomicAdd(yb + (size_t)(mt * 16 + quad * 4 + r) * 128 + k_base + nt * 16 + l16,
                                  acc[mt][nt][r]);
        }
    }
}

// A buffer in FRAG-MAJOR layout (y|Wconv, single bf16 plane).  grid (32) x 256
// PART=1: sums the 16 y_part slices (L2-hot); PART=0: reads ybuf.
template <bool PART>
__global__ __launch_bounds__(256) void k_build_A(
        const float* __restrict__ y, const float* __restrict__ y_part,
        const float* __restrict__ Wconv, u16* __restrict__ Ah, int lay) {
    int b = blockIdx.x;
    for (int idx = threadIdx.x; idx < 12288; idx += 256) {
        int i = idx & 7, l16 = (idx >> 3) & 15, quad = (idx >> 7) & 3,
            ot = (idx >> 9) & 3, ks = idx >> 11;
        int o = ot * 16 + l16;
        int k = ks * 32 + quad * 8 + i;
        float v;
        if (k < 128) {
            if (PART) {
                v = 0.f;
#pragma unroll
                for (int jj = 0; jj < 16; ++jj)
                    v += y_part[(size_t)jj * 262144 + (size_t)b * 8192 + o * 128 + k];
            } else {
                v = y[((size_t)b * DIM + o) * MODE + k];
            }
        } else {
            v = Wconv[(size_t)lay * DIM * DIM + o * DIM + (k - 128)];
        }
        Ah[(size_t)b * 12288 + idx] = to_bf16(v);
    }
}

// ---------------------------------------------------------------------------
// inv_conv: h' = act(A(64x192) @ B(192 x 16384x) + bconv), in-place on h.
// FROZEN at r5's version (best measured: 86.6 us across 9 structural tries).
template <bool DO_MLP>
__global__ __launch_bounds__(256, 4) void k_inv_conv_mfma(
        const u16* __restrict__ Afh,
        const u16* __restrict__ Bfh,
        u16* __restrict__ Hh,
        const float* __restrict__ bconv, int lay,
        const u16* __restrict__ W1h,
        const float* __restrict__ b1, const float* __restrict__ W2,
        const float* __restrict__ b2, float* __restrict__ out) {
    __shared__ u16 sh[12288];   // phase 1: A frags (24KB); phase 2: osh (16KB)
    int t = threadIdx.x;
    int wave = t >> 6, lane = t & 63, quad = lane >> 4, l16 = lane & 15;
    int bid = blockIdx.x;
    int swz = (bid & 7) * 512 + (bid >> 3);
    int b = swz & 31;
    int x0 = (swz >> 5) * 128;
    int xw = wave * 32;

    // issue ALL loads up front: A first, then B (bases, h)
    const u16* afb = Afh + (size_t)b * 12288;
    bf16x8 areg[6];
#pragma unroll
    for (int i = 0; i < 6; ++i)
        areg[i] = *(const bf16x8*)(afb + (size_t)(i * 256 + t) * 8);
    bf16x8 bg[4][2], hf[2][2];
#pragma unroll
    for (int ks = 0; ks < 4; ++ks)
#pragma unroll
        for (int x2 = 0; x2 < 2; ++x2) {
            int xl = xw + x2 * 16 + l16;
            bg[ks][x2] = *(const bf16x8*)(Bfh + (size_t)((ks * 4 + quad) * 16384 + x0 + xl) * 8);
        }
#pragma unroll
    for (int ks = 0; ks < 2; ++ks)
#pragma unroll
        for (int x2 = 0; x2 < 2; ++x2) {
            int xl = xw + x2 * 16 + l16;
            hf[ks][x2] = *(const bf16x8*)(Hh + ((size_t)(b << 14) + x0 + xl) * 64
                                          + ks * 32 + quad * 8);
        }
    __builtin_amdgcn_sched_barrier(0);
    // A regs -> LDS (waits only on the 6 A loads; B still in flight)
#pragma unroll
    for (int i = 0; i < 6; ++i)
        *(bf16x8*)&sh[(i * 256 + t) * 8] = areg[i];
    __syncthreads();   // Ash ready

    f32x4 acc[4][2] = {};
#pragma unroll
    for (int ks = 0; ks < 6; ++ks) {
        bf16x8 afh[4];
#pragma unroll
        for (int ot = 0; ot < 4; ++ot)
            afh[ot] = *(const bf16x8*)&sh[(((ks * 4 + ot) * 4 + quad) * 16 + l16) * 8];
#pragma unroll
        for (int ot = 0; ot < 4; ++ot)
#pragma unroll
            for (int x2 = 0; x2 < 2; ++x2)
                acc[ot][x2] = __builtin_amdgcn_mfma_f32_16x16x32_bf16(
                    afh[ot], ks < 4 ? bg[ks][x2] : hf[ks - 4][x2],
                    acc[ot][x2], 0, 0, 0);
    }
    __syncthreads();   // all Ash reads done -> alias sh as output staging

    // epilogue: bias (+gelu for lay 0/1), pack into sh (wave-private rows)
#pragma unroll
    for (int ot = 0; ot < 4; ++ot) {
        float4 bc = *(const float4*)(bconv + lay * DIM + ot * 16 + quad * 4);
#pragma unroll
        for (int x2 = 0; x2 < 2; ++x2) {
            int xl = xw + x2 * 16 + l16;
            float vr[4] = {acc[ot][x2][0] + bc.x, acc[ot][x2][1] + bc.y,
                           acc[ot][x2][2] + bc.z, acc[ot][x2][3] + bc.w};
            if (!DO_MLP) {
#pragma unroll
                for (int r = 0; r < 4; ++r) vr[r] = gelu_fast(vr[r]);
            }
            ushort4 uh;
            uh.x = to_bf16(vr[0]); uh.y = to_bf16(vr[1]);
            uh.z = to_bf16(vr[2]); uh.w = to_bf16(vr[3]);
            int col = ot * 16 + quad * 4;
            *(ushort4*)&sh[xl * 64 + (col ^ ((xl & 7) << 3))] = uh;
        }
    }

    if (!DO_MLP) {
        __syncthreads();   // cross-wave: dense store covers all rows
#pragma unroll
        for (int it = 0; it < 4; ++it) {
            int idx = it * 256 + t;
            int row = idx >> 3, c8 = (idx & 7) * 8;
            size_t dst = ((size_t)(b << 14) + x0 + row) * 64 + c8;
            *(bf16x8*)(Hh + dst) =
                *(const bf16x8*)&sh[row * 64 + (c8 ^ ((row & 7) << 3))];
        }
        return;
    }

    // ---- fused final MLP (lay 2 only): out = gelu(h'@W1+b1)@W2 + b2 ----
    // each wave reads only its own sh rows -> no barrier needed.
#pragma unroll
    for (int x2 = 0; x2 < 2; ++x2) {
        int xl = xw + x2 * 16 + l16;
        bf16x8 ah[2];
#pragma unroll
        for (int ks = 0; ks < 2; ++ks) {
            int ko = ks * 32 + quad * 8;
            ah[ks] = *(const bf16x8*)&sh[xl * 64 + (ko ^ ((xl & 7) << 3))];
        }
        float vo[4] = {0.f, 0.f, 0.f, 0.f};
#pragma unroll
        for (int ft = 0; ft < 8; ++ft) {
            f32x4 a2 = {};
#pragma unroll
            for (int ks = 0; ks < 2; ++ks) {
                size_t o = (size_t)(ft * 16 + l16) * 64 + ks * 32 + quad * 8;
                bf16x8 bh = *(const bf16x8*)(W1h + o);
                a2 = __builtin_amdgcn_mfma_f32_16x16x32_bf16(ah[ks], bh, a2, 0, 0, 0);
            }
            float bb = b1[ft * 16 + l16];
            float w2 = W2[ft * 16 + l16];
#pragma unroll
            for (int r = 0; r < 4; ++r)
                vo[r] += gelu_fast(a2[r] + bb) * w2;
        }
#pragma unroll
        for (int r = 0; r < 4; ++r) {
            float v = vo[r];
            v += __shfl_xor(v, 1);
            v += __shfl_xor(v, 2);
            v += __shfl_xor(v, 4);
            v += __shfl_xor(v, 8);
            vo[r] = v;
        }
        if (l16 == 0) {
            float bb2 = b2[0];
            float4 o4 = make_float4(vo[0] + bb2, vo[1] + bb2,
                                    vo[2] + bb2, vo[3] + bb2);
            *(float4*)(out + (size_t)b * NXX + x0 + xw + x2 * 16 + quad * 4) = o4;
        }
    }
}

// ---------------------------------------------------------------------------
extern "C" void kernel_launch(void* const* d_in, const int* in_sizes, int n_in,
                              void* d_out, int out_size, void* d_ws, size_t ws_size,
                              hipStream_t stream) {
    const float* x      = (const float*)d_in[0];
    const float* bases  = (const float*)d_in[1];
    const float* wbases = (const float*)d_in[2];
    const float* product= (const float*)d_in[3];
    const float* Dout   = (const float*)d_in[4];
    const float* Din    = (const float*)d_in[5];
    const float* A      = (const float*)d_in[6];
    const float* Bm     = (const float*)d_in[7];
    const float* Wsp    = (const float*)d_in[8];
    const float* Wconv  = (const float*)d_in[9];
    const float* bconv  = (const float*)d_in[10];
    const float* W0     = (const float*)d_in[11];
    const float* b0     = (const float*)d_in[12];
    const float* W1     = (const float*)d_in[13];
    const float* b1     = (const float*)d_in[14];
    const float* W2     = (const float*)d_in[15];
    const float* b2     = (const float*)d_in[16];
    float* out = (float*)d_out;

    const size_t need     = 79314944;            // base allocations
    const size_t need_big = need + 33554432;     // + xh_part(32MB); y_part aliases
    if (ws_size < need) {
        k_zero<<<dim3((out_size + 255) / 256), dim3(256), 0, stream>>>(out, out_size);
        return;
    }
    const bool part = (ws_size >= need_big);

    char* W = (char*)d_ws;
    size_t off = 0;
    auto alloc = [&](size_t bytes) { void* p = W + off; off += bytes; return p; };
    u16*   Hbf      = (u16*)alloc(524288);
    u16*   WsT      = (u16*)alloc(393216);
    u16*   bases_hi = (u16*)alloc(4194304);
    u16*   wbT_hi   = (u16*)alloc(4194304);
    u16*   Abuf_hi  = (u16*)alloc(786432);
    float* ybuf     = (float*)alloc(1048576);
    float* xh       = (float*)alloc(1048576);   // must follow ybuf (joint zeroing)
    u16*   h_hi     = (u16*)alloc(67108864);
    u16*   w1t_hi   = (u16*)alloc(16384);
    float* xh_part  = part ? (float*)alloc(33554432) : nullptr;
    float* y_part   = xh_part;   // aliases: xh_part dead after k_reduce_xh

    k_build_H<<<dim3(1024), dim3(256), 0, stream>>>(Dout, Din, product, A, Bm, Hbf);
    k_setup_wst<<<dim3(768), dim3(256), 0, stream>>>(Wsp, WsT);
    k_setup_bases<<<dim3(8192), dim3(256), 0, stream>>>(bases, bases_hi);
    k_setup_wbT<<<dim3(512, 4), dim3(256), 0, stream>>>(wbases, wbT_hi);
    k_setup_w1t<<<dim3(32), dim3(256), 0, stream>>>(W1, w1t_hi);
    k_fc0<<<dim3(512, B_SZ), dim3(256), 0, stream>>>(x, W0, b0, h_hi);

    for (int lay = 0; lay < N_LAY; ++lay) {
        int last = (lay == N_LAY - 1);
        if (part) {
            k_spectral_mfma<true><<<dim3(B_SZ, 32), dim3(256), 0, stream>>>(
                h_hi, wbT_hi, xh, xh_part);
            k_reduce_xh<<<dim3(256), dim3(256), 0, stream>>>(xh_part, xh);
            k_hmix_mfma<true><<<dim3(B_SZ, JM), dim3(256), 0, stream>>>(
                xh, Hbf, WsT, ybuf, y_part, lay);
            k_build_A<true><<<dim3(B_SZ), dim3(256), 0, stream>>>(
                ybuf, y_part, Wconv, Abuf_hi, lay);
        } else {
            k_zero4<<<dim3(512), dim3(256), 0, stream>>>(ybuf);   // ybuf + xh
            k_spectral_mfma<false><<<dim3(B_SZ, 16), dim3(256), 0, stream>>>(
                h_hi, wbT_hi, xh, nullptr);
            k_hmix_mfma<false><<<dim3(B_SZ, JM), dim3(256), 0, stream>>>(
                xh, Hbf, WsT, ybuf, nullptr, lay);
            k_build_A<false><<<dim3(B_SZ), dim3(256), 0, stream>>>(
                ybuf, nullptr, Wconv, Abuf_hi, lay);
        }
        dim3 g(4096), blk(256);
        if (last)
            k_inv_conv_mfma<true><<<g, blk, 0, stream>>>(
                Abuf_hi, bases_hi, h_hi, bconv, lay,
                w1t_hi, b1, W2, b2, out);
        else
            k_inv_conv_mfma<false><<<g, blk, 0, stream>>>(
                Abuf_hi, bases_hi, h_hi, bconv, lay,
                w1t_hi, b1, W2, b2, out);
    }
}

// Round 14
// 444.231 us; speedup vs baseline: 1.0253x; 1.0253x over previous
//
#include <hip/hip_runtime.h>
#include <hip/hip_bf16.h>
#include <math.h>

#define B_SZ   32
#define NXX    16384
#define IN_DIM 3
#define DIM    64
#define JM     16
#define MODE   128
#define RANKK  4
#define FC_DIM 128
#define N_LAY  3

typedef __attribute__((ext_vector_type(8))) short bf16x8;
typedef __attribute__((ext_vector_type(4))) float f32x4;
typedef unsigned short u16;

// Fast gelu: v * sigmoid(2u), u = sqrt(2/pi)*(v + 0.044715 v^3).
__device__ __forceinline__ float gelu_fast(float v) {
    float p = v * (0.7978845608f + 0.0356774081f * v * v);
    float e = __expf(-2.f * p);
    return v * __builtin_amdgcn_rcpf(1.f + e);
}
__device__ __forceinline__ u16 to_bf16(float v) {
    __hip_bfloat16 b = __float2bfloat16(v);
    return *(u16*)&b;
}

// ---------------------------------------------------------------------------
__global__ __launch_bounds__(256) void k_zero(float* __restrict__ p, int n) {
    int i = blockIdx.x * 256 + threadIdx.x;
    if (i < n) p[i] = 0.f;
}

// float4 variant for the per-layer 2MB clear (ybuf+xh).  grid 512 x 256.
__global__ __launch_bounds__(256) void k_zero4(float* __restrict__ p) {
    int i = blockIdx.x * 256 + threadIdx.x;
    *(float4*)(p + (size_t)i * 4) = make_float4(0.f, 0.f, 0.f, 0.f);
}

// H[j,k,l] bf16 row-major (l contig = A-frag-ready for m=k, kk=l).
__global__ __launch_bounds__(256) void k_build_H(
        const float* __restrict__ Dout, const float* __restrict__ Din,
        const float* __restrict__ product, const float* __restrict__ A,
        const float* __restrict__ Bm, u16* __restrict__ Hbf) {
    int idx = blockIdx.x * 256 + threadIdx.x;
    int j = idx >> 14;
    int k = (idx >> 7) & 127;
    int l = idx & 127;
    float v = Dout[j * MODE + k] * Din[j * MODE + l] * product[k * MODE + l];
#pragma unroll
    for (int r = 0; r < RANKK; ++r)
        v += A[(j * RANKK + r) * MODE + k] * Bm[(j * RANKK + r) * MODE + l];
    Hbf[idx] = to_bf16(v);
}

// WsT[lay][j][o][i] = Wsp[lay][i][o][j] bf16 (i contig).  grid 768 x 256.
__global__ __launch_bounds__(256) void k_setup_wst(
        const float* __restrict__ Wsp, u16* __restrict__ WsT) {
    int idx = blockIdx.x * 256 + threadIdx.x;   // ((lay*16+j)*64+o)*64+i
    int i = idx & 63, o = (idx >> 6) & 63, j = (idx >> 12) & 15, lay = idx >> 16;
    WsT[idx] = to_bf16(Wsp[(((size_t)lay * 64 + i) * 64 + o) * 16 + j]);
}

// bases (fp32 [x][k]) -> FRAG-MAJOR single bf16 plane.  grid 8192 x 256.
__global__ __launch_bounds__(256) void k_setup_bases(
        const float* __restrict__ bases, u16* __restrict__ bh) {
    int idx = blockIdx.x * 256 + threadIdx.x;
    int x = idx >> 7, k = idx & 127;
    size_t off = (size_t)(k >> 3) * 131072 + (size_t)x * 8 + (k & 7);
    bh[off] = to_bf16(bases[idx]);
}

// wbT[l][x] = wbases[x][l], single bf16 plane.  grid (512, 4) x 256, LDS-tiled.
__global__ __launch_bounds__(256) void k_setup_wbT(
        const float* __restrict__ wb, u16* __restrict__ Th) {
    __shared__ float tile[32][33];
    int bx = blockIdx.x, bl = blockIdx.y;
    int t = threadIdx.x;
    int i = t >> 5, jj = t & 31;
#pragma unroll
    for (int r = 0; r < 4; ++r)
        tile[i + r * 8][jj] = wb[(size_t)(bx * 32 + i + r * 8) * MODE + bl * 32 + jj];
    __syncthreads();
#pragma unroll
    for (int r = 0; r < 4; ++r) {
        int l = bl * 32 + i + r * 8;
        int x = bx * 32 + jj;
        Th[(size_t)l * NXX + x] = to_bf16(tile[jj][i + r * 8]);
    }
}

// W1T[f*64+c] = W1[c*128+f] single bf16 plane.  grid 32 x 256
__global__ __launch_bounds__(256) void k_setup_w1t(
        const float* __restrict__ W1, u16* __restrict__ wh) {
    int i = blockIdx.x * 256 + threadIdx.x;
    int f = i >> 6, c = i & 63;
    wh[i] = to_bf16(W1[c * FC_DIM + f]);
}

// fc0: h[b,x,c] (single bf16 plane), coalesced ushort8 stores.
// grid (512, 32) x 256.
__global__ __launch_bounds__(256) void k_fc0(
        const float* __restrict__ x, const float* __restrict__ W0,
        const float* __restrict__ b0, u16* __restrict__ hh) {
    __shared__ float w0s[IN_DIM * DIM + DIM];
    int t = threadIdx.x;
    if (t < IN_DIM * DIM) w0s[t] = W0[t];
    if (t < DIM) w0s[IN_DIM * DIM + t] = b0[t];
    __syncthreads();
    int b = blockIdx.y;
    int xi = blockIdx.x * 32 + (t >> 3);
    int c8 = (t & 7) * 8;
    const float* xp = x + ((size_t)b * NXX + xi) * IN_DIM;
    float x0 = xp[0], x1 = xp[1], x2 = xp[2];
    u16 rh[8];
#pragma unroll
    for (int i = 0; i < 8; ++i) {
        int c = c8 + i;
        float v = x0 * w0s[c] + x1 * w0s[DIM + c] + x2 * w0s[2 * DIM + c]
                + w0s[3 * DIM + c];
        rh[i] = to_bf16(v);
    }
    size_t o = ((size_t)(b << 14) + xi) * 64 + c8;
    *(ushort4*)(hh + o)     = make_ushort4(rh[0], rh[1], rh[2], rh[3]);
    *(ushort4*)(hh + o + 4) = make_ushort4(rh[4], rh[5], rh[6], rh[7]);
}

// ---------------------------------------------------------------------------
// Spectral via MFMA: xh[b][c][l] += sum_x h[b][x][c] * wbases[x][l]
// 1024-x slab per block, grid (32 b, 16 slabs), XCD swizzle, reg prefetch.
// Double-buffered Ash -> one barrier per 64-x step.
// PART=1: plain-store partial to xh_part; PART=0: atomicAdd (ws fallback).
#define SPAD 72
template <bool PART>
__global__ __launch_bounds__(256) void k_spectral_mfma(
        const u16* __restrict__ Hh,
        const u16* __restrict__ Wh,
        float* __restrict__ xh,
        float* __restrict__ xh_part) {
    __shared__ u16 Ash[2][64 * SPAD];
    int t = threadIdx.x;
    int wave = t >> 6, lane = t & 63, quad = lane >> 4, l16 = lane & 15;
    int lin = blockIdx.y * 32 + blockIdx.x;          // 0..511
    int swz = (lin & 7) * 64 + (lin >> 3);           // XCD-contiguous
    int b = swz & 31;
    int slab = swz >> 5;
    int x0 = slab * 1024;
    int cq = (t & 15) * 4;
    int xq = (t >> 4) * 4;
    int colw = (xq + ((t & 7) << 3)) & 63;
    const u16* srch = Hh + ((size_t)(b << 14) + x0 + xq) * 64 + cq;
    int l0 = wave * 32;
    const u16* w0h = Wh + (size_t)(l0 + l16) * NXX + x0;
    const u16* w1h = Wh + (size_t)(l0 + 16 + l16) * NXX + x0;
    ushort4 r0, r1, r2, r3;
    {
        const u16* s = srch;
        r0 = *(const ushort4*)(s);
        r1 = *(const ushort4*)(s + 64);
        r2 = *(const ushort4*)(s + 128);
        r3 = *(const ushort4*)(s + 192);
    }
    f32x4 acc[4][2] = {};
    int cur = 0;
    for (int kt = 0; kt < 1024; kt += 64) {
        u16* A = &Ash[cur][0];
        *(ushort4*)&A[(cq + 0) * SPAD + colw] = make_ushort4(r0.x, r1.x, r2.x, r3.x);
        *(ushort4*)&A[(cq + 1) * SPAD + colw] = make_ushort4(r0.y, r1.y, r2.y, r3.y);
        *(ushort4*)&A[(cq + 2) * SPAD + colw] = make_ushort4(r0.z, r1.z, r2.z, r3.z);
        *(ushort4*)&A[(cq + 3) * SPAD + colw] = make_ushort4(r0.w, r1.w, r2.w, r3.w);
        if (kt + 64 < 1024) {   // prefetch next slab; completes during MFMA
            const u16* s = srch + (size_t)(kt + 64) * 64;
            r0 = *(const ushort4*)(s);
            r1 = *(const ushort4*)(s + 64);
            r2 = *(const ushort4*)(s + 128);
            r3 = *(const ushort4*)(s + 192);
        }
        __builtin_amdgcn_sched_barrier(0);
        __syncthreads();        // single barrier per step (dbuf)
#pragma unroll
        for (int k0 = 0; k0 < 64; k0 += 32) {
            bf16x8 afh[4];
#pragma unroll
            for (int ct = 0; ct < 4; ++ct) {
                int rr = ct * 16 + l16;
                int ro = rr * SPAD + (((k0 + quad * 8) + (((rr >> 2) & 7) << 3)) & 63);
                afh[ct] = *(const bf16x8*)&A[ro];
            }
            int go = kt + k0 + quad * 8;
            bf16x8 b0h = *(const bf16x8*)(w0h + go);
            bf16x8 b1h = *(const bf16x8*)(w1h + go);
#pragma unroll
            for (int ct = 0; ct < 4; ++ct) {
                acc[ct][0] = __builtin_amdgcn_mfma_f32_16x16x32_bf16(afh[ct], b0h, acc[ct][0], 0, 0, 0);
                acc[ct][1] = __builtin_amdgcn_mfma_f32_16x16x32_bf16(afh[ct], b1h, acc[ct][1], 0, 0, 0);
            }
        }
        cur ^= 1;
    }
    if (PART) {
        float* xp = xh_part + ((size_t)slab * 32 + b) * 8192;
#pragma unroll
        for (int ct = 0; ct < 4; ++ct)
#pragma unroll
            for (int lt = 0; lt < 2; ++lt)
#pragma unroll
                for (int r = 0; r < 4; ++r)
                    xp[(ct * 16 + quad * 4 + r) * 128 + l0 + lt * 16 + l16] =
                        acc[ct][lt][r];
    } else {
        float* xb = xh + (size_t)(b << 6) * 128;
#pragma unroll
        for (int ct = 0; ct < 4; ++ct)
#pragma unroll
            for (int lt = 0; lt < 2; ++lt)
#pragma unroll
                for (int r = 0; r < 4; ++r)
                    atomicAdd(xb + (size_t)(ct * 16 + quad * 4 + r) * 128 + l0 + lt * 16 + l16,
                              acc[ct][lt][r]);
    }
}

// reduce 16 xh partials -> xh.  grid 256 x 256 (float4 per thread).
__global__ __launch_bounds__(256) void k_reduce_xh(
        const float* __restrict__ part, float* __restrict__ xh) {
    size_t i4 = ((size_t)blockIdx.x * 256 + threadIdx.x) * 4;
    float4 s = make_float4(0.f, 0.f, 0.f, 0.f);
#pragma unroll
    for (int sl = 0; sl < 16; ++sl) {
        float4 v = *(const float4*)(part + (size_t)sl * 262144 + i4);
        s.x += v.x; s.y += v.y; s.z += v.z; s.w += v.w;
    }
    *(float4*)(xh + i4) = s;
}

// ---------------------------------------------------------------------------
// hmix via MFMA.  One block per (b, j):
//   phase 1: T[k][i] = sum_l H[j][k][l] * xh[b][i][l]
//   phase 2: y[o][k] contribution for this j.
// No inter-phase barrier (Ts rows wave-private).
#define XPAD 136
#define TPAD 72
template <bool PART>
__global__ __launch_bounds__(256) void k_hmix_mfma(
        const float* __restrict__ xh, const u16* __restrict__ Hbf,
        const u16* __restrict__ WsT, float* __restrict__ y,
        float* __restrict__ y_part, int lay) {
    __shared__ u16 xsb[64 * XPAD];   // [i][l]
    __shared__ u16 Ts[128 * TPAD];   // [k][i], rows wave-private
    int t = threadIdx.x;
    int wave = t >> 6, lane = t & 63, quad = lane >> 4, l16 = lane & 15;
    int b = blockIdx.x, j = blockIdx.y;
    const float* xb = xh + (size_t)b * DIM * MODE;
#pragma unroll
    for (int it = 0; it < 8; ++it) {
        int idx = it * 1024 + t * 4;
        float4 v = *(const float4*)(xb + idx);
        ushort4 uh;
        uh.x = to_bf16(v.x); uh.y = to_bf16(v.y);
        uh.z = to_bf16(v.z); uh.w = to_bf16(v.w);
        *(ushort4*)&xsb[(idx >> 7) * XPAD + (idx & 127)] = uh;
    }
    __syncthreads();
    int k_base = wave * 32;
    // phase 1
    {
        f32x4 acc[2][4] = {};
        const u16* Hj = Hbf + (size_t)j * MODE * MODE;
#pragma unroll
        for (int l0 = 0; l0 < 128; l0 += 32) {
            bf16x8 af[2], bf[4];
#pragma unroll
            for (int mt = 0; mt < 2; ++mt)
                af[mt] = *(const bf16x8*)(Hj + (size_t)(k_base + mt * 16 + l16) * 128 + l0 + quad * 8);
#pragma unroll
            for (int nt = 0; nt < 4; ++nt)
                bf[nt] = *(const bf16x8*)&xsb[(nt * 16 + l16) * XPAD + l0 + quad * 8];
#pragma unroll
            for (int mt = 0; mt < 2; ++mt)
#pragma unroll
                for (int nt = 0; nt < 4; ++nt)
                    acc[mt][nt] = __builtin_amdgcn_mfma_f32_16x16x32_bf16(af[mt], bf[nt], acc[mt][nt], 0, 0, 0);
        }
#pragma unroll
        for (int mt = 0; mt < 2; ++mt)
#pragma unroll
            for (int nt = 0; nt < 4; ++nt)
#pragma unroll
                for (int r = 0; r < 4; ++r)
                    Ts[(k_base + mt * 16 + quad * 4 + r) * TPAD + nt * 16 + l16] =
                        to_bf16(acc[mt][nt][r]);
    }
    // no barrier: phase 2 reads only this wave's own Ts rows
    {
        f32x4 acc[4][2] = {};
        const u16* Wj = WsT + ((size_t)lay * JM + j) * DIM * DIM;
#pragma unroll
        for (int i0 = 0; i0 < 64; i0 += 32) {
            bf16x8 af[4], bf[2];
#pragma unroll
            for (int mt = 0; mt < 4; ++mt)
                af[mt] = *(const bf16x8*)(Wj + (size_t)(mt * 16 + l16) * 64 + i0 + quad * 8);
#pragma unroll
            for (int nt = 0; nt < 2; ++nt)
                bf[nt] = *(const bf16x8*)&Ts[(k_base + nt * 16 + l16) * TPAD + i0 + quad * 8];
#pragma unroll
            for (int mt = 0; mt < 4; ++mt)
#pragma unroll
                for (int nt = 0; nt < 2; ++nt)
                    acc[mt][nt] = __builtin_amdgcn_mfma_f32_16x16x32_bf16(af[mt], bf[nt], acc[mt][nt], 0, 0, 0);
        }
        if (PART) {
            float* yp = y_part + ((size_t)j * 32 + b) * 8192;
#pragma unroll
            for (int mt = 0; mt < 4; ++mt)
#pragma unroll
                for (int nt = 0; nt < 2; ++nt)
#pragma unroll
                    for (int r = 0; r < 4; ++r)
                        yp[(mt * 16 + quad * 4 + r) * 128 + k_base + nt * 16 + l16] =
                            acc[mt][nt][r];
        } else {
            float* yb = y + (size_t)b * DIM * MODE;
#pragma unroll
            for (int mt = 0; mt < 4; ++mt)
#pragma unroll
                for (int nt = 0; nt < 2; ++nt)
#pragma unroll
                    for (int r = 0; r < 4; ++r)
                        atomicAdd(yb + (size_t)(mt * 16 + quad * 4 + r) * 128 + k_base + nt * 16 + l16,
                                  acc[mt][nt][r]);
        }
    }
}

// A buffer in FRAG-MAJOR layout (y|Wconv, single bf16 plane).  grid (32) x 256
// PART=1: sums the 16 y_part slices (L2-hot); PART=0: reads ybuf.
template <bool PART>
__global__ __launch_bounds__(256) void k_build_A(
        const float* __restrict__ y, const float* __restrict__ y_part,
        const float* __restrict__ Wconv, u16* __restrict__ Ah, int lay) {
    int b = blockIdx.x;
    for (int idx = threadIdx.x; idx < 12288; idx += 256) {
        int i = idx & 7, l16 = (idx >> 3) & 15, quad = (idx >> 7) & 3,
            ot = (idx >> 9) & 3, ks = idx >> 11;
        int o = ot * 16 + l16;
        int k = ks * 32 + quad * 8 + i;
        float v;
        if (k < 128) {
            if (PART) {
                v = 0.f;
#pragma unroll
                for (int jj = 0; jj < 16; ++jj)
                    v += y_part[(size_t)jj * 262144 + (size_t)b * 8192 + o * 128 + k];
            } else {
                v = y[((size_t)b * DIM + o) * MODE + k];
            }
        } else {
            v = Wconv[(size_t)lay * DIM * DIM + o * DIM + (k - 128)];
        }
        Ah[(size_t)b * 12288 + idx] = to_bf16(v);
    }
}

// ---------------------------------------------------------------------------
// inv_conv: h' = act(A(64x192) @ B(192 x 16384x) + bconv), in-place on h.
// FROZEN at r5's version (best measured: 86.6 us across 9 structural tries).
template <bool DO_MLP>
__global__ __launch_bounds__(256, 4) void k_inv_conv_mfma(
        const u16* __restrict__ Afh,
        const u16* __restrict__ Bfh,
        u16* __restrict__ Hh,
        const float* __restrict__ bconv, int lay,
        const u16* __restrict__ W1h,
        const float* __restrict__ b1, const float* __restrict__ W2,
        const float* __restrict__ b2, float* __restrict__ out) {
    __shared__ u16 sh[12288];   // phase 1: A frags (24KB); phase 2: osh (16KB)
    int t = threadIdx.x;
    int wave = t >> 6, lane = t & 63, quad = lane >> 4, l16 = lane & 15;
    int bid = blockIdx.x;
    int swz = (bid & 7) * 512 + (bid >> 3);
    int b = swz & 31;
    int x0 = (swz >> 5) * 128;
    int xw = wave * 32;

    // issue ALL loads up front: A first, then B (bases, h)
    const u16* afb = Afh + (size_t)b * 12288;
    bf16x8 areg[6];
#pragma unroll
    for (int i = 0; i < 6; ++i)
        areg[i] = *(const bf16x8*)(afb + (size_t)(i * 256 + t) * 8);
    bf16x8 bg[4][2], hf[2][2];
#pragma unroll
    for (int ks = 0; ks < 4; ++ks)
#pragma unroll
        for (int x2 = 0; x2 < 2; ++x2) {
            int xl = xw + x2 * 16 + l16;
            bg[ks][x2] = *(const bf16x8*)(Bfh + (size_t)((ks * 4 + quad) * 16384 + x0 + xl) * 8);
        }
#pragma unroll
    for (int ks = 0; ks < 2; ++ks)
#pragma unroll
        for (int x2 = 0; x2 < 2; ++x2) {
            int xl = xw + x2 * 16 + l16;
            hf[ks][x2] = *(const bf16x8*)(Hh + ((size_t)(b << 14) + x0 + xl) * 64
                                          + ks * 32 + quad * 8);
        }
    __builtin_amdgcn_sched_barrier(0);
    // A regs -> LDS (waits only on the 6 A loads; B still in flight)
#pragma unroll
    for (int i = 0; i < 6; ++i)
        *(bf16x8*)&sh[(i * 256 + t) * 8] = areg[i];
    __syncthreads();   // Ash ready

    f32x4 acc[4][2] = {};
#pragma unroll
    for (int ks = 0; ks < 6; ++ks) {
        bf16x8 afh[4];
#pragma unroll
        for (int ot = 0; ot < 4; ++ot)
            afh[ot] = *(const bf16x8*)&sh[(((ks * 4 + ot) * 4 + quad) * 16 + l16) * 8];
#pragma unroll
        for (int ot = 0; ot < 4; ++ot)
#pragma unroll
            for (int x2 = 0; x2 < 2; ++x2)
                acc[ot][x2] = __builtin_amdgcn_mfma_f32_16x16x32_bf16(
                    afh[ot], ks < 4 ? bg[ks][x2] : hf[ks - 4][x2],
                    acc[ot][x2], 0, 0, 0);
    }
    __syncthreads();   // all Ash reads done -> alias sh as output staging

    // epilogue: bias (+gelu for lay 0/1), pack into sh (wave-private rows)
#pragma unroll
    for (int ot = 0; ot < 4; ++ot) {
        float4 bc = *(const float4*)(bconv + lay * DIM + ot * 16 + quad * 4);
#pragma unroll
        for (int x2 = 0; x2 < 2; ++x2) {
            int xl = xw + x2 * 16 + l16;
            float vr[4] = {acc[ot][x2][0] + bc.x, acc[ot][x2][1] + bc.y,
                           acc[ot][x2][2] + bc.z, acc[ot][x2][3] + bc.w};
            if (!DO_MLP) {
#pragma unroll
                for (int r = 0; r < 4; ++r) vr[r] = gelu_fast(vr[r]);
            }
            ushort4 uh;
            uh.x = to_bf16(vr[0]); uh.y = to_bf16(vr[1]);
            uh.z = to_bf16(vr[2]); uh.w = to_bf16(vr[3]);
            int col = ot * 16 + quad * 4;
            *(ushort4*)&sh[xl * 64 + (col ^ ((xl & 7) << 3))] = uh;
        }
    }

    if (!DO_MLP) {
        __syncthreads();   // cross-wave: dense store covers all rows
#pragma unroll
        for (int it = 0; it < 4; ++it) {
            int idx = it * 256 + t;
            int row = idx >> 3, c8 = (idx & 7) * 8;
            size_t dst = ((size_t)(b << 14) + x0 + row) * 64 + c8;
            *(bf16x8*)(Hh + dst) =
                *(const bf16x8*)&sh[row * 64 + (c8 ^ ((row & 7) << 3))];
        }
        return;
    }

    // ---- fused final MLP (lay 2 only): out = gelu(h'@W1+b1)@W2 + b2 ----
    // each wave reads only its own sh rows -> no barrier needed.
#pragma unroll
    for (int x2 = 0; x2 < 2; ++x2) {
        int xl = xw + x2 * 16 + l16;
        bf16x8 ah[2];
#pragma unroll
        for (int ks = 0; ks < 2; ++ks) {
            int ko = ks * 32 + quad * 8;
            ah[ks] = *(const bf16x8*)&sh[xl * 64 + (ko ^ ((xl & 7) << 3))];
        }
        float vo[4] = {0.f, 0.f, 0.f, 0.f};
#pragma unroll
        for (int ft = 0; ft < 8; ++ft) {
            f32x4 a2 = {};
#pragma unroll
            for (int ks = 0; ks < 2; ++ks) {
                size_t o = (size_t)(ft * 16 + l16) * 64 + ks * 32 + quad * 8;
                bf16x8 bh = *(const bf16x8*)(W1h + o);
                a2 = __builtin_amdgcn_mfma_f32_16x16x32_bf16(ah[ks], bh, a2, 0, 0, 0);
            }
            float bb = b1[ft * 16 + l16];
            float w2 = W2[ft * 16 + l16];
#pragma unroll
            for (int r = 0; r < 4; ++r)
                vo[r] += gelu_fast(a2[r] + bb) * w2;
        }
#pragma unroll
        for (int r = 0; r < 4; ++r) {
            float v = vo[r];
            v += __shfl_xor(v, 1);
            v += __shfl_xor(v, 2);
            v += __shfl_xor(v, 4);
            v += __shfl_xor(v, 8);
            vo[r] = v;
        }
        if (l16 == 0) {
            float bb2 = b2[0];
            float4 o4 = make_float4(vo[0] + bb2, vo[1] + bb2,
                                    vo[2] + bb2, vo[3] + bb2);
            *(float4*)(out + (size_t)b * NXX + x0 + xw + x2 * 16 + quad * 4) = o4;
        }
    }
}

// ---------------------------------------------------------------------------
extern "C" void kernel_launch(void* const* d_in, const int* in_sizes, int n_in,
                              void* d_out, int out_size, void* d_ws, size_t ws_size,
                              hipStream_t stream) {
    const float* x      = (const float*)d_in[0];
    const float* bases  = (const float*)d_in[1];
    const float* wbases = (const float*)d_in[2];
    const float* product= (const float*)d_in[3];
    const float* Dout   = (const float*)d_in[4];
    const float* Din    = (const float*)d_in[5];
    const float* A      = (const float*)d_in[6];
    const float* Bm     = (const float*)d_in[7];
    const float* Wsp    = (const float*)d_in[8];
    const float* Wconv  = (const float*)d_in[9];
    const float* bconv  = (const float*)d_in[10];
    const float* W0     = (const float*)d_in[11];
    const float* b0     = (const float*)d_in[12];
    const float* W1     = (const float*)d_in[13];
    const float* b1     = (const float*)d_in[14];
    const float* W2     = (const float*)d_in[15];
    const float* b2     = (const float*)d_in[16];
    float* out = (float*)d_out;

    const size_t need     = 79314944;                 // base allocations
    const size_t need_big = need + 16777216 + 16777216;  // + xh_part + y_part
    if (ws_size < need) {
        k_zero<<<dim3((out_size + 255) / 256), dim3(256), 0, stream>>>(out, out_size);
        return;
    }
    const bool part = (ws_size >= need_big);

    char* W = (char*)d_ws;
    size_t off = 0;
    auto alloc = [&](size_t bytes) { void* p = W + off; off += bytes; return p; };
    u16*   Hbf      = (u16*)alloc(524288);
    u16*   WsT      = (u16*)alloc(393216);
    u16*   bases_hi = (u16*)alloc(4194304);
    u16*   wbT_hi   = (u16*)alloc(4194304);
    u16*   Abuf_hi  = (u16*)alloc(786432);
    float* ybuf     = (float*)alloc(1048576);
    float* xh       = (float*)alloc(1048576);   // must follow ybuf (joint zeroing)
    u16*   h_hi     = (u16*)alloc(67108864);
    u16*   w1t_hi   = (u16*)alloc(16384);
    float* xh_part  = part ? (float*)alloc(16777216) : nullptr;
    float* y_part   = part ? (float*)alloc(16777216) : nullptr;

    k_build_H<<<dim3(1024), dim3(256), 0, stream>>>(Dout, Din, product, A, Bm, Hbf);
    k_setup_wst<<<dim3(768), dim3(256), 0, stream>>>(Wsp, WsT);
    k_setup_bases<<<dim3(8192), dim3(256), 0, stream>>>(bases, bases_hi);
    k_setup_wbT<<<dim3(512, 4), dim3(256), 0, stream>>>(wbases, wbT_hi);
    k_setup_w1t<<<dim3(32), dim3(256), 0, stream>>>(W1, w1t_hi);
    k_fc0<<<dim3(512, B_SZ), dim3(256), 0, stream>>>(x, W0, b0, h_hi);

    for (int lay = 0; lay < N_LAY; ++lay) {
        int last = (lay == N_LAY - 1);
        if (part) {
            k_spectral_mfma<true><<<dim3(B_SZ, 16), dim3(256), 0, stream>>>(
                h_hi, wbT_hi, xh, xh_part);
            k_reduce_xh<<<dim3(256), dim3(256), 0, stream>>>(xh_part, xh);
            k_hmix_mfma<true><<<dim3(B_SZ, JM), dim3(256), 0, stream>>>(
                xh, Hbf, WsT, ybuf, y_part, lay);
            k_build_A<true><<<dim3(B_SZ), dim3(256), 0, stream>>>(
                ybuf, y_part, Wconv, Abuf_hi, lay);
        } else {
            k_zero4<<<dim3(512), dim3(256), 0, stream>>>(ybuf);   // ybuf + xh
            k_spectral_mfma<false><<<dim3(B_SZ, 16), dim3(256), 0, stream>>>(
                h_hi, wbT_hi, xh, nullptr);
            k_hmix_mfma<false><<<dim3(B_SZ, JM), dim3(256), 0, stream>>>(
                xh, Hbf, WsT, ybuf, nullptr, lay);
            k_build_A<false><<<dim3(B_SZ), dim3(256), 0, stream>>>(
                ybuf, nullptr, Wconv, Abuf_hi, lay);
        }
        dim3 g(4096), blk(256);
        if (last)
            k_inv_conv_mfma<true><<<g, blk, 0, stream>>>(
                Abuf_hi, bases_hi, h_hi, bconv, lay,
                w1t_hi, b1, W2, b2, out);
        else
            k_inv_conv_mfma<false><<<g, blk, 0, stream>>>(
                Abuf_hi, bases_hi, h_hi, bconv, lay,
                w1t_hi, b1, W2, b2, out);
    }
}